// Round 9
// baseline (168.197 us; speedup 1.0000x reference)
//
#include <hip/hip_runtime.h>

#define VOCAB 100000
#define EMBED 128
#define MAX_PATH 20
#define BATCH 32768
#define WPB 4                    // waves per block (block = 256 threads)
#define NBLOCKS (BATCH / WPB)    // 8192

// R9: L3 pre-warm + unchanged R8 loss kernel.
// R2/R5/R8 all plateau at ~42us with VALU<=28%, HBM<=38%; R6 (max in-flight)
// and R7 (5x TLP) regress -> throughput ceiling, not latency. Arithmetic:
// FETCH ~121 MB is compulsory, and the harness's 256MB ws-poison fill
// flushes L3 before every timed launch, so the kernel re-pulls 121 MB from
// HBM at random 512B/80B granule (~45-55% DRAM efficiency ~ 2.9 TB/s) = 42us.
// Fix: stream-touch inner_vec/paths/codes (one float4 per 64B line,
// sequential = full streaming efficiency) to refill L3, then run the gather
// kernel against warm L3. in_emb NOT warmed (only ~28% of rows used; warming
// 51MB to save 14MB of random reads is a net loss).
__global__ __launch_bounds__(256) void warm_kernel(
    const float4* __restrict__ inner_vec, const float4* __restrict__ paths,
    const float4* __restrict__ codes, float* __restrict__ sink)
{
    const int tid = blockIdx.x * 256 + threadIdx.x;
    const int nth = gridDim.x * 256;
    float s = 0.f;
    // inner_vec: 99999*128 floats = 3,199,968 float4 -> one per 4 (64B line)
    for (int i = tid; i < 3199968 / 4; i += nth) s += inner_vec[i * 4].x;
    // paths, codes: 100000*20 = 2,000,000 elems = 500,000 float4 each
    for (int i = tid; i < 500000 / 4; i += nth) s += paths[i * 4].x;
    for (int i = tid; i < 500000 / 4; i += nth) s += codes[i * 4].x;
    if (s == 1.2345e33f) sink[0] = s;   // unprovable -> loads kept
}

// Loss kernel: identical to R8 (single-variable experiment).
__global__ __launch_bounds__(256, 6) void hs_loss_kernel(
    const int* __restrict__ center, const int* __restrict__ target,
    const float* __restrict__ in_emb, const float* __restrict__ inner_vec,
    const int* __restrict__ paths, const float* __restrict__ codes,
    float* __restrict__ partials)
{
    __shared__ float4 lds_buf[WPB * 384];   // 3 chunks x 2 KB per wave
    __shared__ float  ws[WPB];

    const int wave = threadIdx.x >> 6;
    const int lane = threadIdx.x & 63;
    const int g    = lane >> 4;   // group 0..3
    const int gl   = lane & 15;   // lane within group
    const int b = blockIdx.x * WPB + wave;

    const int c = center[b];
    const int t = target[b];

    const float4* hp = (const float4*)(in_emb + (size_t)c * EMBED);
    const float4 h0 = hp[gl];
    const float4 h1 = hp[gl + 16];

    const int base = t * MAX_PATH + g;
    int   p[5];
    float cd[5];
    #pragma unroll
    for (int j = 0; j < 5; ++j) {
        p[j]  = paths[base + 4 * j];
        cd[j] = codes[base + 4 * j];
    }
    const bool do3 = __ballot(cd[3] != 0.f) != 0ull;
    const bool do4 = __ballot(cd[4] != 0.f) != 0ull;

    // register gathers: chunks 0,1
    const float4* v0 = (const float4*)(inner_vec + (size_t)p[0] * EMBED);
    const float4 r00 = v0[gl], r01 = v0[gl + 16];
    const float4* v1 = (const float4*)(inner_vec + (size_t)p[1] * EMBED);
    const float4 r10 = v1[gl], r11 = v1[gl + 16];

    // async LDS stages: chunks 2,3,4
    float4* myl = lds_buf + wave * 384;
    {
        const float* src = inner_vec + (size_t)p[2] * EMBED + 4 * gl;
        __builtin_amdgcn_global_load_lds(
            (const __attribute__((address_space(1))) unsigned int*)(src),
            (__attribute__((address_space(3))) unsigned int*)(myl),
            16, 0, 0);
        __builtin_amdgcn_global_load_lds(
            (const __attribute__((address_space(1))) unsigned int*)(src + 64),
            (__attribute__((address_space(3))) unsigned int*)(myl + 64),
            16, 0, 0);
    }
    if (do3) {
        const float* src = inner_vec + (size_t)p[3] * EMBED + 4 * gl;
        __builtin_amdgcn_global_load_lds(
            (const __attribute__((address_space(1))) unsigned int*)(src),
            (__attribute__((address_space(3))) unsigned int*)(myl + 128),
            16, 0, 0);
        __builtin_amdgcn_global_load_lds(
            (const __attribute__((address_space(1))) unsigned int*)(src + 64),
            (__attribute__((address_space(3))) unsigned int*)(myl + 192),
            16, 0, 0);
    }
    if (do4) {
        const float* src = inner_vec + (size_t)p[4] * EMBED + 4 * gl;
        __builtin_amdgcn_global_load_lds(
            (const __attribute__((address_space(1))) unsigned int*)(src),
            (__attribute__((address_space(3))) unsigned int*)(myl + 256),
            16, 0, 0);
        __builtin_amdgcn_global_load_lds(
            (const __attribute__((address_space(1))) unsigned int*)(src + 64),
            (__attribute__((address_space(3))) unsigned int*)(myl + 320),
            16, 0, 0);
    }

    float acc = 0.f;
    #pragma unroll
    for (int j = 0; j < 2; ++j) {
        const float4 a0 = (j == 0) ? r00 : r10;
        const float4 a1 = (j == 0) ? r01 : r11;
        float d = h0.x * a0.x;
        d = fmaf(h0.y, a0.y, d);
        d = fmaf(h0.z, a0.z, d);
        d = fmaf(h0.w, a0.w, d);
        float e = h1.x * a1.x;
        e = fmaf(h1.y, a1.y, e);
        e = fmaf(h1.z, a1.z, e);
        e = fmaf(h1.w, a1.w, e);
        d += e;
        d += __shfl_xor(d, 1, 64);
        d += __shfl_xor(d, 2, 64);
        d += __shfl_xor(d, 4, 64);
        d += __shfl_xor(d, 8, 64);
        const float x  = cd[j] * d;
        const float ls = fminf(x, 0.f) - __logf(1.f + __expf(-fabsf(x)));
        acc = fmaf(fabsf(cd[j]), ls, acc);
    }

    __builtin_amdgcn_s_waitcnt(0xF70);      // per-wave vmcnt(0) drain
    __builtin_amdgcn_sched_barrier(0);

    #pragma unroll
    for (int j = 2; j < 5; ++j) {
        if (j == 3 && !do3) continue;
        if (j == 4 && !do4) continue;
        const float4 a0 = myl[(j - 2) * 128 + lane];
        const float4 a1 = myl[(j - 2) * 128 + 64 + lane];
        float d = h0.x * a0.x;
        d = fmaf(h0.y, a0.y, d);
        d = fmaf(h0.z, a0.z, d);
        d = fmaf(h0.w, a0.w, d);
        float e = h1.x * a1.x;
        e = fmaf(h1.y, a1.y, e);
        e = fmaf(h1.z, a1.z, e);
        e = fmaf(h1.w, a1.w, e);
        d += e;
        d += __shfl_xor(d, 1, 64);
        d += __shfl_xor(d, 2, 64);
        d += __shfl_xor(d, 4, 64);
        d += __shfl_xor(d, 8, 64);
        const float x  = cd[j] * d;
        const float ls = fminf(x, 0.f) - __logf(1.f + __expf(-fabsf(x)));
        acc = fmaf(fabsf(cd[j]), ls, acc);
    }

    acc += __shfl_xor(acc, 16, 64);
    acc += __shfl_xor(acc, 32, 64);

    if (lane == 0) ws[wave] = -acc;
    __syncthreads();
    if (threadIdx.x == 0) {
        partials[blockIdx.x] = ws[0] + ws[1] + ws[2] + ws[3];
    }
}

__global__ __launch_bounds__(256) void hs_reduce_kernel(
    const float* __restrict__ partials, float* __restrict__ out)
{
    const float4* p4 = (const float4*)partials;
    float s = 0.f;
    #pragma unroll
    for (int i = 0; i < NBLOCKS / 4 / 256; ++i) {
        const float4 v = p4[i * 256 + threadIdx.x];
        s += (v.x + v.y) + (v.z + v.w);
    }
    #pragma unroll
    for (int off = 32; off; off >>= 1) s += __shfl_xor(s, off, 64);
    __shared__ float ws[4];
    const int wave = threadIdx.x >> 6;
    const int lane = threadIdx.x & 63;
    if (lane == 0) ws[wave] = s;
    __syncthreads();
    if (threadIdx.x == 0) {
        out[0] = (ws[0] + ws[1] + ws[2] + ws[3]) / (float)BATCH;
    }
}

extern "C" void kernel_launch(void* const* d_in, const int* in_sizes, int n_in,
                              void* d_out, int out_size, void* d_ws, size_t ws_size,
                              hipStream_t stream) {
    const int*   center    = (const int*)d_in[0];
    const int*   target    = (const int*)d_in[1];
    const float* in_emb    = (const float*)d_in[2];
    const float* inner_vec = (const float*)d_in[3];
    const int*   paths     = (const int*)d_in[4];
    const float* codes     = (const float*)d_in[5];
    // d_in[6] (masks) intentionally unused: mask == |code|
    float* out = (float*)d_out;
    float* partials = (float*)d_ws;           // 8192 floats = 32 KB
    float* sink     = (float*)d_ws + NBLOCKS; // warm-kernel DCE guard

    warm_kernel<<<1024, 256, 0, stream>>>(
        (const float4*)inner_vec, (const float4*)paths, (const float4*)codes,
        sink);
    hs_loss_kernel<<<NBLOCKS, 256, 0, stream>>>(
        center, target, in_emb, inner_vec, paths, codes, partials);
    hs_reduce_kernel<<<1, 256, 0, stream>>>(partials, out);
}

// Round 10
// 159.600 us; speedup vs baseline: 1.0539x; 1.0539x over previous
//
#include <hip/hip_runtime.h>

#define VOCAB 100000
#define EMBED 128
#define MAX_PATH 20
#define BATCH 32768
#define WPB 4                    // waves per block (block = 256 threads)
#define NBLOCKS (BATCH / WPB)    // 8192

// R10 = R8 restored (drop R9's warm kernel: it cost 12us to save ~6us).
// Final structure. Evidence trail:
//  - R2/R5/R8 (three different structures) all plateau 41.5-43.8us at
//    FETCH ~121MB (compulsory), VALU<=28%, HBM<=38% -> ceiling is the
//    fabric random-gather delivery path (~8.6 TB/s aggregate), not VALU,
//    not occupancy, not HBM streaming.
//  - R6 (max in-flight via full LDS staging): regressed (occupancy+barrier).
//  - R7 (5x TLP, node-parallel): regressed (+48MB HBM re-reads).
//  - R9 (L3 pre-warm): loss kernel gains ~6us but warm costs 12us -> net loss,
//    proving the limit is delivery-path throughput, not DRAM granule
//    efficiency.
// Design: hybrid register + async-LDS gather staging, per-wave sync only;
// every vmem instr 256B-contiguous per 16-lane group; mask == |code|;
// wave-uniform skip of fully-padded chunks; no device-scope fences.
__global__ __launch_bounds__(256, 6) void hs_loss_kernel(
    const int* __restrict__ center, const int* __restrict__ target,
    const float* __restrict__ in_emb, const float* __restrict__ inner_vec,
    const int* __restrict__ paths, const float* __restrict__ codes,
    float* __restrict__ partials)
{
    __shared__ float4 lds_buf[WPB * 384];   // 3 chunks x 2 KB per wave
    __shared__ float  ws[WPB];

    const int wave = threadIdx.x >> 6;
    const int lane = threadIdx.x & 63;
    const int g    = lane >> 4;   // group 0..3
    const int gl   = lane & 15;   // lane within group
    const int b = blockIdx.x * WPB + wave;

    const int c = center[b];
    const int t = target[b];

    const float4* hp = (const float4*)(in_emb + (size_t)c * EMBED);
    const float4 h0 = hp[gl];
    const float4 h1 = hp[gl + 16];

    const int base = t * MAX_PATH + g;
    int   p[5];
    float cd[5];
    #pragma unroll
    for (int j = 0; j < 5; ++j) {
        p[j]  = paths[base + 4 * j];
        cd[j] = codes[base + 4 * j];
    }
    const bool do3 = __ballot(cd[3] != 0.f) != 0ull;
    const bool do4 = __ballot(cd[4] != 0.f) != 0ull;

    // register gathers: chunks 0,1
    const float4* v0 = (const float4*)(inner_vec + (size_t)p[0] * EMBED);
    const float4 r00 = v0[gl], r01 = v0[gl + 16];
    const float4* v1 = (const float4*)(inner_vec + (size_t)p[1] * EMBED);
    const float4 r10 = v1[gl], r11 = v1[gl + 16];

    // async LDS stages: chunks 2,3,4 (two 1024B instrs each, 0 VGPR)
    float4* myl = lds_buf + wave * 384;
    {
        const float* src = inner_vec + (size_t)p[2] * EMBED + 4 * gl;
        __builtin_amdgcn_global_load_lds(
            (const __attribute__((address_space(1))) unsigned int*)(src),
            (__attribute__((address_space(3))) unsigned int*)(myl),
            16, 0, 0);
        __builtin_amdgcn_global_load_lds(
            (const __attribute__((address_space(1))) unsigned int*)(src + 64),
            (__attribute__((address_space(3))) unsigned int*)(myl + 64),
            16, 0, 0);
    }
    if (do3) {
        const float* src = inner_vec + (size_t)p[3] * EMBED + 4 * gl;
        __builtin_amdgcn_global_load_lds(
            (const __attribute__((address_space(1))) unsigned int*)(src),
            (__attribute__((address_space(3))) unsigned int*)(myl + 128),
            16, 0, 0);
        __builtin_amdgcn_global_load_lds(
            (const __attribute__((address_space(1))) unsigned int*)(src + 64),
            (__attribute__((address_space(3))) unsigned int*)(myl + 192),
            16, 0, 0);
    }
    if (do4) {
        const float* src = inner_vec + (size_t)p[4] * EMBED + 4 * gl;
        __builtin_amdgcn_global_load_lds(
            (const __attribute__((address_space(1))) unsigned int*)(src),
            (__attribute__((address_space(3))) unsigned int*)(myl + 256),
            16, 0, 0);
        __builtin_amdgcn_global_load_lds(
            (const __attribute__((address_space(1))) unsigned int*)(src + 64),
            (__attribute__((address_space(3))) unsigned int*)(myl + 320),
            16, 0, 0);
    }

    float acc = 0.f;
    // chunks 0,1 from registers
    #pragma unroll
    for (int j = 0; j < 2; ++j) {
        const float4 a0 = (j == 0) ? r00 : r10;
        const float4 a1 = (j == 0) ? r01 : r11;
        float d = h0.x * a0.x;
        d = fmaf(h0.y, a0.y, d);
        d = fmaf(h0.z, a0.z, d);
        d = fmaf(h0.w, a0.w, d);
        float e = h1.x * a1.x;
        e = fmaf(h1.y, a1.y, e);
        e = fmaf(h1.z, a1.z, e);
        e = fmaf(h1.w, a1.w, e);
        d += e;
        d += __shfl_xor(d, 1, 64);
        d += __shfl_xor(d, 2, 64);
        d += __shfl_xor(d, 4, 64);
        d += __shfl_xor(d, 8, 64);
        const float x  = cd[j] * d;
        const float ls = fminf(x, 0.f) - __logf(1.f + __expf(-fabsf(x)));
        acc = fmaf(fabsf(cd[j]), ls, acc);
    }

    // per-wave drain of my LDS stages (NOT a block barrier)
    __builtin_amdgcn_s_waitcnt(0xF70);      // vmcnt(0)
    __builtin_amdgcn_sched_barrier(0);

    // chunks 2,3,4 from LDS (contiguous ds_read_b128, conflict-free)
    #pragma unroll
    for (int j = 2; j < 5; ++j) {
        if (j == 3 && !do3) continue;
        if (j == 4 && !do4) continue;
        const float4 a0 = myl[(j - 2) * 128 + lane];
        const float4 a1 = myl[(j - 2) * 128 + 64 + lane];
        float d = h0.x * a0.x;
        d = fmaf(h0.y, a0.y, d);
        d = fmaf(h0.z, a0.z, d);
        d = fmaf(h0.w, a0.w, d);
        float e = h1.x * a1.x;
        e = fmaf(h1.y, a1.y, e);
        e = fmaf(h1.z, a1.z, e);
        e = fmaf(h1.w, a1.w, e);
        d += e;
        d += __shfl_xor(d, 1, 64);
        d += __shfl_xor(d, 2, 64);
        d += __shfl_xor(d, 4, 64);
        d += __shfl_xor(d, 8, 64);
        const float x  = cd[j] * d;
        const float ls = fminf(x, 0.f) - __logf(1.f + __expf(-fabsf(x)));
        acc = fmaf(fabsf(cd[j]), ls, acc);
    }

    acc += __shfl_xor(acc, 16, 64);
    acc += __shfl_xor(acc, 32, 64);

    if (lane == 0) ws[wave] = -acc;
    __syncthreads();
    if (threadIdx.x == 0) {
        partials[blockIdx.x] = ws[0] + ws[1] + ws[2] + ws[3];
    }
}

__global__ __launch_bounds__(256) void hs_reduce_kernel(
    const float* __restrict__ partials, float* __restrict__ out)
{
    const float4* p4 = (const float4*)partials;
    float s = 0.f;
    #pragma unroll
    for (int i = 0; i < NBLOCKS / 4 / 256; ++i) {
        const float4 v = p4[i * 256 + threadIdx.x];
        s += (v.x + v.y) + (v.z + v.w);
    }
    #pragma unroll
    for (int off = 32; off; off >>= 1) s += __shfl_xor(s, off, 64);
    __shared__ float ws[4];
    const int wave = threadIdx.x >> 6;
    const int lane = threadIdx.x & 63;
    if (lane == 0) ws[wave] = s;
    __syncthreads();
    if (threadIdx.x == 0) {
        out[0] = (ws[0] + ws[1] + ws[2] + ws[3]) / (float)BATCH;
    }
}

extern "C" void kernel_launch(void* const* d_in, const int* in_sizes, int n_in,
                              void* d_out, int out_size, void* d_ws, size_t ws_size,
                              hipStream_t stream) {
    const int*   center    = (const int*)d_in[0];
    const int*   target    = (const int*)d_in[1];
    const float* in_emb    = (const float*)d_in[2];
    const float* inner_vec = (const float*)d_in[3];
    const int*   paths     = (const int*)d_in[4];
    const float* codes     = (const float*)d_in[5];
    // d_in[6] (masks) intentionally unused: mask == |code|
    float* out = (float*)d_out;
    float* partials = (float*)d_ws;   // 8192 floats = 32 KB scratch

    hs_loss_kernel<<<NBLOCKS, 256, 0, stream>>>(
        center, target, in_emb, inner_vec, paths, codes, partials);
    hs_reduce_kernel<<<1, 256, 0, stream>>>(partials, out);
}